// Round 3
// baseline (111.089 us; speedup 1.0000x reference)
//
#include <hip/hip_runtime.h>

typedef __bf16 bf16;
typedef __attribute__((ext_vector_type(4))) __bf16 bf16x4;
typedef __attribute__((ext_vector_type(8))) __bf16 bf16x8;
typedef __attribute__((ext_vector_type(4))) float f32x4;

#define MFMA16(a, b, c) __builtin_amdgcn_mfma_f32_16x16x32_bf16((a), (b), (c), 0, 0, 0)

// ---------------------------------------------------------------------------
// Kernel 1: W [o][c] fp32 -> hi/lo bf16 split, same [o][c] layout.
// ---------------------------------------------------------------------------
__global__ __launch_bounds__(256) void prep_w_kernel(const float* __restrict__ Wq,
                                                     const float* __restrict__ Wk,
                                                     const int* __restrict__ flag,
                                                     bf16* __restrict__ Wbh,
                                                     bf16* __restrict__ Wbl) {
  const int z = blockIdx.y;
  const float* src = (z == 0) ? Wq : ((flag[0] != 0) ? Wq : Wk);
  int i = (blockIdx.x * 256 + threadIdx.x) * 4;  // 0..16383
  float4 v = *(const float4*)(src + i);
  bf16x4 hi, lo;
  hi[0] = (bf16)v.x; lo[0] = (bf16)(v.x - (float)hi[0]);
  hi[1] = (bf16)v.y; lo[1] = (bf16)(v.y - (float)hi[1]);
  hi[2] = (bf16)v.z; lo[2] = (bf16)(v.z - (float)hi[2]);
  hi[3] = (bf16)v.w; lo[3] = (bf16)(v.w - (float)hi[3]);
  *(bf16x4*)(Wbh + z * 16384 + i) = hi;
  *(bf16x4*)(Wbl + z * 16384 + i) = lo;
}

// ---------------------------------------------------------------------------
// Kernel 1b: V convert, kf fp32 [b][c][q] -> Vb bf16 (same layout).
// 4096 blocks x 256 thr x 8 elem.
// ---------------------------------------------------------------------------
__global__ __launch_bounds__(256) void vconv_kernel(const float* __restrict__ kf,
                                                    bf16* __restrict__ Vb) {
  int i = (blockIdx.x * 256 + threadIdx.x) * 8;
  float4 f0 = *(const float4*)(kf + i);
  float4 f1 = *(const float4*)(kf + i + 4);
  bf16x8 v;
  v[0] = (bf16)f0.x; v[1] = (bf16)f0.y; v[2] = (bf16)f0.z; v[3] = (bf16)f0.w;
  v[4] = (bf16)f1.x; v[5] = (bf16)f1.y; v[6] = (bf16)f1.z; v[7] = (bf16)f1.w;
  *(bf16x8*)(Vb + i) = v;
}

// ---------------------------------------------------------------------------
// Kernel 2: MFMA projection. out[b][p][o] = sum_c x[b][c][p] * W[o][c] + bias.
// A = W (hi+lo bf16 split), B = x (fp32 loaded per-lane, cvt to bf16).
// grid (8 p-tiles of 128, 32 b, 2 z) x 256 thr.
// ---------------------------------------------------------------------------
__global__ __launch_bounds__(256) void proj_kernel(const float* __restrict__ qf,
                                                   const float* __restrict__ kf,
                                                   const bf16* __restrict__ Wbh,
                                                   const bf16* __restrict__ Wbl,
                                                   const float* __restrict__ bq,
                                                   const float* __restrict__ bk,
                                                   const int* __restrict__ flag,
                                                   bf16* __restrict__ Qp,
                                                   bf16* __restrict__ Kp) {
  const int b = blockIdx.y, z = blockIdx.z;
  const float* x = z ? kf : qf;
  const bf16* Wh = Wbh + z * 16384;
  const bf16* Wl = Wbl + z * 16384;
  const float* bias = z ? (flag[0] ? bq : bk) : bq;
  bf16* dst = z ? Kp : Qp;

  const int t = threadIdx.x;
  const int w = t >> 6, lane = t & 63;
  const int g = lane >> 4, l16 = lane & 15;
  const int wo = w >> 1, wp = w & 1;
  const int o0 = wo << 5;
  const int pbase = (blockIdx.x << 7) + (wp << 6);

  f32x4 acc[2][4];
#pragma unroll
  for (int ot = 0; ot < 2; ++ot) {
    float4 bv = *(const float4*)(bias + o0 + (ot << 4) + (g << 2));
#pragma unroll
    for (int pt = 0; pt < 4; ++pt) acc[ot][pt] = (f32x4){bv.x, bv.y, bv.z, bv.w};
  }

  const float* xb = x + ((((b << 8) + (g << 3)) << 10) + pbase + l16);
  const bf16* whb = Wh + ((o0 + l16) << 8) + (g << 3);
  const bf16* wlb = Wl + ((o0 + l16) << 8) + (g << 3);

  for (int kk = 0; kk < 8; ++kk) {
    bf16x8 ah[2], al[2];
#pragma unroll
    for (int ot = 0; ot < 2; ++ot) {
      ah[ot] = *(const bf16x8*)(whb + (ot << 12) + (kk << 5));
      al[ot] = *(const bf16x8*)(wlb + (ot << 12) + (kk << 5));
    }
    const float* xk = xb + (kk << 15);
#pragma unroll
    for (int pt = 0; pt < 4; ++pt) {
      float xv[8];
#pragma unroll
      for (int j = 0; j < 8; ++j) xv[j] = xk[(j << 10) + (pt << 4)];
      bf16x8 xf;
#pragma unroll
      for (int j = 0; j < 8; ++j) xf[j] = (bf16)xv[j];
#pragma unroll
      for (int ot = 0; ot < 2; ++ot) {
        acc[ot][pt] = MFMA16(ah[ot], xf, acc[ot][pt]);
        acc[ot][pt] = MFMA16(al[ot], xf, acc[ot][pt]);
      }
    }
  }

#pragma unroll
  for (int ot = 0; ot < 2; ++ot)
#pragma unroll
    for (int pt = 0; pt < 4; ++pt) {
      bf16x4 q4;
#pragma unroll
      for (int r = 0; r < 4; ++r) q4[r] = (bf16)acc[ot][pt][r];
      int p = pbase + (pt << 4) + l16;
      *(bf16x4*)(dst + (((b << 10) + p) << 6) + o0 + (ot << 4) + (g << 2)) = q4;
    }
}

// ---------------------------------------------------------------------------
// Kernel 3: fused flash attention, channel-split.
// grid (32 = 16 p-tiles x 2 ch-halves, 32 batches) x 256 thr (4 waves).
// p-tile = 64 rows. Every wave: S+softmax for rows [16w,16w+16).
// PV: wave w covers channels [ch*128 + 32w, +32) ; V read direct from global.
// ---------------------------------------------------------------------------
__global__ __launch_bounds__(256, 4) void attn_kernel(const bf16* __restrict__ Vb,
                                                      const bf16* __restrict__ Qp,
                                                      const bf16* __restrict__ Kp,
                                                      float* __restrict__ out) {
  const int b = blockIdx.y;
  const int ptile = blockIdx.x >> 1;
  const int ch = blockIdx.x & 1;
  const int p0 = ptile << 6;
  const int t = threadIdx.x;
  const int w = t >> 6, lane = t & 63;
  const int g = lane >> 4, l16 = lane & 15;

  __shared__ __align__(16) unsigned char sK[8192];  // [64 q][64 o] bf16 swizzled
  __shared__ __align__(16) unsigned char sP[8192];  // [64 row][64 q] bf16 swizzled
  __shared__ float sSc[64];
  __shared__ float sL[64];

  // Q fragments for this wave's 16 rows (A-operand: row=l16, k=8*g+j)
  bf16x8 aq0, aq1;
  {
    const int prow = p0 + (w << 4) + l16;
    const bf16* qb = Qp + (((b << 10) + prow) << 6) + (g << 3);
    aq0 = *(const bf16x8*)qb;
    aq1 = *(const bf16x8*)(qb + 32);
  }

  const int cbase = (ch << 7) + (w << 5);  // wave's 32-channel slice base
  const bf16* vb0 = Vb + (((b << 8) + cbase + l16) << 10) + (g << 3);

  f32x4 acc[4][2];  // [row-group][channel-sub]
#pragma unroll
  for (int i = 0; i < 4; ++i)
#pragma unroll
    for (int j = 0; j < 2; ++j) acc[i][j] = (f32x4){0.f, 0.f, 0.f, 0.f};
  float m_[4], l_[4];
#pragma unroll
  for (int r = 0; r < 4; ++r) { m_[r] = -1e30f; l_[r] = 0.f; }

  for (int kt = 0; kt < 16; ++kt) {
    const int q0 = kt << 6;
    __syncthreads();  // (A) prev iter's sK(S) and sP(pa) reads complete
    // ---- stage K tile: 64q x 64o bf16 (8 KB), reg path, swizzled ----
#pragma unroll
    for (int it = 0; it < 2; ++it) {
      int task = it * 256 + t;
      int q = task >> 3, oc = task & 7;
      bf16x8 v = *(const bf16x8*)(Kp + (((b << 10) + q0 + q) << 6) + (oc << 3));
      *(bf16x8*)(sK + ((q * 128 + oc * 16) ^ ((q & 7) << 4))) = v;
    }
    __syncthreads();  // (B) staging visible

    // ---- S = Q K^T for this wave's 16 rows ----
    f32x4 s[4];
#pragma unroll
    for (int qf = 0; qf < 4; ++qf) {
      int q = (qf << 4) + l16;
      bf16x8 k0 = *(const bf16x8*)(sK + ((q * 128 + g * 16) ^ ((q & 7) << 4)));
      bf16x8 k1 = *(const bf16x8*)(sK + ((q * 128 + g * 16 + 64) ^ ((q & 7) << 4)));
      f32x4 z4 = (f32x4){0.f, 0.f, 0.f, 0.f};
      z4 = MFMA16(aq0, k0, z4);
      s[qf] = MFMA16(aq1, k1, z4);
    }
    // ---- online softmax with defer-max (THR=8) ----
    float tm[4], sc[4], rs[4];
#pragma unroll
    for (int r = 0; r < 4; ++r) {
      tm[r] = fmaxf(fmaxf(s[0][r], s[1][r]), fmaxf(s[2][r], s[3][r]));
      tm[r] = fmaxf(tm[r], __shfl_xor(tm[r], 1));
      tm[r] = fmaxf(tm[r], __shfl_xor(tm[r], 2));
      tm[r] = fmaxf(tm[r], __shfl_xor(tm[r], 4));
      tm[r] = fmaxf(tm[r], __shfl_xor(tm[r], 8));
      float mn = fmaxf(m_[r], tm[r]);
      if (mn - m_[r] <= 8.f) mn = m_[r];  // defer: keep old max (exp<=e^8)
      sc[r] = __expf(m_[r] - mn);         // exactly 1.0f when deferred
      m_[r] = mn;
    }
#pragma unroll
    for (int qf = 0; qf < 4; ++qf)
#pragma unroll
      for (int r = 0; r < 4; ++r) s[qf][r] = __expf(s[qf][r] - m_[r]);
#pragma unroll
    for (int r = 0; r < 4; ++r) {
      rs[r] = (s[0][r] + s[1][r]) + (s[2][r] + s[3][r]);
      rs[r] += __shfl_xor(rs[r], 1);
      rs[r] += __shfl_xor(rs[r], 2);
      rs[r] += __shfl_xor(rs[r], 4);
      rs[r] += __shfl_xor(rs[r], 8);
      l_[r] = l_[r] * sc[r] + rs[r];
    }
    // ---- publish P (bf16) and per-row rescale factors ----
    if (l16 == 0) {
#pragma unroll
      for (int r = 0; r < 4; ++r) sSc[(w << 4) + (g << 2) + r] = sc[r];
    }
#pragma unroll
    for (int qf = 0; qf < 4; ++qf)
#pragma unroll
      for (int r = 0; r < 4; ++r) {
        int row = (w << 4) + (g << 2) + r;
        int col = (qf << 4) + l16;
        *(bf16*)(sP + ((row * 128 + col * 2) ^ ((row & 7) << 4))) = (bf16)s[qf][r];
      }
    __syncthreads();  // (C) P + scales visible to all waves

    // ---- conditional rescale (skipped when all deferred) ----
#pragma unroll
    for (int rg = 0; rg < 4; ++rg) {
      float f0 = sSc[(rg << 4) + (g << 2) + 0];
      float f1 = sSc[(rg << 4) + (g << 2) + 1];
      float f2 = sSc[(rg << 4) + (g << 2) + 2];
      float f3 = sSc[(rg << 4) + (g << 2) + 3];
      if (!(f0 == 1.f && f1 == 1.f && f2 == 1.f && f3 == 1.f)) {
#pragma unroll
        for (int cl = 0; cl < 2; ++cl) {
          acc[rg][cl][0] *= f0;
          acc[rg][cl][1] *= f1;
          acc[rg][cl][2] *= f2;
          acc[rg][cl][3] *= f3;
        }
      }
    }
    // ---- load P A-fragments (all 64 rows) ----
    bf16x8 pa[4][2];
#pragma unroll
    for (int rg = 0; rg < 4; ++rg) {
      int row = (rg << 4) + l16;
      pa[rg][0] = *(const bf16x8*)(sP + ((row * 128 + g * 16) ^ ((row & 7) << 4)));
      pa[rg][1] = *(const bf16x8*)(sP + ((row * 128 + g * 16 + 64) ^ ((row & 7) << 4)));
    }
    // ---- PV: V B-fragments direct from global (L2-resident) ----
#pragma unroll
    for (int cl = 0; cl < 2; ++cl) {
      const bf16* vp = vb0 + (cl << 14) + q0;
      bf16x8 v0 = *(const bf16x8*)vp;
      bf16x8 v1 = *(const bf16x8*)(vp + 32);
#pragma unroll
      for (int rg = 0; rg < 4; ++rg) {
        acc[rg][cl] = MFMA16(pa[rg][0], v0, acc[rg][cl]);
        acc[rg][cl] = MFMA16(pa[rg][1], v1, acc[rg][cl]);
      }
    }
  }

  // ---- epilogue: share l, normalize, direct coalesced-at-wave stores ----
  if (l16 == 0) {
#pragma unroll
    for (int r = 0; r < 4; ++r) sL[(w << 4) + (g << 2) + r] = l_[r];
  }
  __syncthreads();
#pragma unroll
  for (int rg = 0; rg < 4; ++rg) {
    float i0 = 1.f / sL[(rg << 4) + (g << 2) + 0];
    float i1 = 1.f / sL[(rg << 4) + (g << 2) + 1];
    float i2 = 1.f / sL[(rg << 4) + (g << 2) + 2];
    float i3 = 1.f / sL[(rg << 4) + (g << 2) + 3];
#pragma unroll
    for (int cl = 0; cl < 2; ++cl) {
      int c = cbase + (cl << 4) + l16;
      float4 vst;
      vst.x = acc[rg][cl][0] * i0;
      vst.y = acc[rg][cl][1] * i1;
      vst.z = acc[rg][cl][2] * i2;
      vst.w = acc[rg][cl][3] * i3;
      *(float4*)(out + (((b << 8) + c) << 10) + p0 + (rg << 4) + (g << 2)) = vst;
    }
  }
}

// ---------------------------------------------------------------------------
extern "C" void kernel_launch(void* const* d_in, const int* in_sizes, int n_in,
                              void* d_out, int out_size, void* d_ws, size_t ws_size,
                              hipStream_t stream) {
  const float* qf = (const float*)d_in[0];
  const float* kf = (const float*)d_in[1];
  const float* Wq = (const float*)d_in[2];
  const float* bq = (const float*)d_in[3];
  const float* Wk = (const float*)d_in[4];
  const float* bk = (const float*)d_in[5];
  // d_in[6] = vis_CA (unused)
  const int* flag = (const int*)d_in[7];  // same_WqWk
  float* out = (float*)d_out;

  char* ws = (char*)d_ws;
  bf16* Qp = (bf16*)ws;                          // 4 MiB: [32][1024][64] bf16
  bf16* Kp = (bf16*)(ws + (4u << 20));           // 4 MiB
  bf16* Wbh = (bf16*)(ws + (8u << 20));          // 64 KiB: [2][64][256] bf16
  bf16* Wbl = (bf16*)(ws + (8u << 20) + 65536);  // 64 KiB
  bf16* Vb = (bf16*)(ws + (9u << 20));           // 16 MiB: [32][256][1024] bf16

  prep_w_kernel<<<dim3(16, 2), 256, 0, stream>>>(Wq, Wk, flag, Wbh, Wbl);
  vconv_kernel<<<4096, 256, 0, stream>>>(kf, Vb);
  proj_kernel<<<dim3(8, 32, 2), 256, 0, stream>>>(qf, kf, Wbh, Wbl, bq, bk, flag, Qp, Kp);
  attn_kernel<<<dim3(32, 32), 256, 0, stream>>>(Vb, Qp, Kp, out);
}